// Round 9
// baseline (2447.660 us; speedup 1.0000x reference)
//
#include <hip/hip_runtime.h>
#include <cstdint>
#include <cstddef>

// Problem constants
#define kSEQ 100
#define kB   200
#define kNP  512
#define kNG  4096
#define kMP  256     // padded M for recurrent/encoder GEMMs
#define KSPLIT 8

typedef _Float16 f16_t;
typedef f16_t f16x8 __attribute__((ext_vector_type(8)));
typedef f16_t f16x4 __attribute__((ext_vector_type(4)));
typedef float f32x4 __attribute__((ext_vector_type(4)));

// ---------------------------------------------------------------------------
// Convert fp32 -> fp16 (RTN).  n8 = number of 8-float groups.
// ---------------------------------------------------------------------------
__global__ __launch_bounds__(256)
void k_half(const float* __restrict__ src, f16_t* __restrict__ dst, int n8) {
    int i = blockIdx.x * 256 + threadIdx.x;
    if (i >= n8) return;
    const float4* s = (const float4*)src + (size_t)i * 2;
    float4 v0 = s[0], v1 = s[1];
    f16x8 h;
    h[0] = (f16_t)v0.x; h[1] = (f16_t)v0.y; h[2] = (f16_t)v0.z; h[3] = (f16_t)v0.w;
    h[4] = (f16_t)v1.x; h[5] = (f16_t)v1.y; h[6] = (f16_t)v1.z; h[7] = (f16_t)v1.w;
    *(f16x8*)(dst + (size_t)i * 8) = h;
}

// ---------------------------------------------------------------------------
// Single-product fp16 MFMA GEMM (r8 proven structure: LDS staging with XOR
// swizzle, 128x128 tile, 4 waves of 64x64, fp16 partials, 200-row pitch).
// CHANGE vs r8: XCD-colocated flat-grid decode — each XCD owns 4 fixed
// n-tiles (4.2 MB whh slice), so across both m-tiles, all 8 k-chunks, and
// all 100 steps that slice stays resident in its XCD's 4 MB L2.
// Grid: flat 512 blocks -> 2 blocks/CU.
// ---------------------------------------------------------------------------
__global__ __launch_bounds__(256)
void k_gemm_f16(const f16_t* __restrict__ A, int lda,
                const f16_t* __restrict__ B, int ldb,
                f16_t* __restrict__ part, int kPerChunk) {
    __shared__ __align__(16) f16_t sA[128 * 64];
    __shared__ __align__(16) f16_t sB[128 * 64];

    // XCD-colocated decode (MI355X: blockIdx round-robins over 8 XCDs)
    const int bid    = blockIdx.x;        // 0..511
    const int xcd    = bid & 7;
    const int idx    = bid >> 3;          // 0..63
    const int n_tile = xcd * 4 + (idx & 3);   // 0..31 : 4 n-tiles per XCD
    const int rem    = idx >> 2;          // 0..15
    const int kc     = rem >> 1;          // 0..7
    const int m_tile = rem & 1;           // 0..1

    const int tid  = threadIdx.x;
    const int lane = tid & 63;
    const int wid  = tid >> 6;
    const int wr   = wid >> 1;   // wave row (0..1)
    const int wc   = wid & 1;    // wave col (0..1)
    const int m0   = m_tile * 128;
    const int n0   = n_tile * 128;
    const int kBase = kc * kPerChunk;

    f32x4 acc[4][4];
#pragma unroll
    for (int i = 0; i < 4; i++)
#pragma unroll
        for (int j = 0; j < 4; j++) acc[i][j] = (f32x4){0.f, 0.f, 0.f, 0.f};

    const int sr = tid >> 1;          // staging row 0..127
    const int sc = (tid & 1) * 32;    // staging col offset (f16 elems)
    const unsigned int swzrow = ((unsigned)sr & 7u) << 4;
    const unsigned int sbase  = (unsigned)sr * 128u + (unsigned)(tid & 1) * 64u;

    for (int kb = 0; kb < kPerChunk; kb += 64) {
        const int k0 = kBase + kb;
        __syncthreads();
        {
            const uint4* gA = (const uint4*)(A + (size_t)(m0 + sr) * (size_t)lda + k0 + sc);
            const uint4* gB = (const uint4*)(B + (size_t)(n0 + sr) * (size_t)ldb + k0 + sc);
#pragma unroll
            for (int i = 0; i < 4; i++) {
                unsigned int off = (sbase + (unsigned)i * 16u) ^ swzrow;
                *(uint4*)((char*)sA + off) = gA[i];
                *(uint4*)((char*)sB + off) = gB[i];
            }
        }
        __syncthreads();
#pragma unroll
        for (int ks2 = 0; ks2 < 2; ks2++) {
            f16x8 a[4], b[4];
            const unsigned int klane = (unsigned)(lane >> 4) * 16u + (unsigned)ks2 * 64u;
#pragma unroll
            for (int fm = 0; fm < 4; fm++) {
                const unsigned int row = (unsigned)(wr * 64 + fm * 16 + (lane & 15));
                const unsigned int off = (row * 128u + klane) ^ ((row & 7u) << 4);
                a[fm] = *(const f16x8*)((const char*)sA + off);
            }
#pragma unroll
            for (int fn = 0; fn < 4; fn++) {
                const unsigned int row = (unsigned)(wc * 64 + fn * 16 + (lane & 15));
                const unsigned int off = (row * 128u + klane) ^ ((row & 7u) << 4);
                b[fn] = *(const f16x8*)((const char*)sB + off);
            }
#pragma unroll
            for (int fm = 0; fm < 4; fm++)
#pragma unroll
                for (int fn = 0; fn < 4; fn++)
                    acc[fm][fn] = __builtin_amdgcn_mfma_f32_16x16x32_f16(a[fm], b[fn], acc[fm][fn], 0, 0, 0);
        }
    }

    // fp16 partial, 200-row pitch, rows >= kB skipped
    f16_t* po = part + (size_t)kc * ((size_t)kB * kNG);
#pragma unroll
    for (int fm = 0; fm < 4; fm++)
#pragma unroll
        for (int fn = 0; fn < 4; fn++) {
            const int row0 = m0 + wr * 64 + fm * 16 + ((lane >> 4) << 2);
            const int col  = n0 + wc * 64 + fn * 16 + (lane & 15);
#pragma unroll
            for (int j = 0; j < 4; j++) {
                const int row = row0 + j;
                if (row < kB)
                    po[(size_t)row * kNG + col] = (f16_t)acc[fm][fn][j];
            }
        }
}

// ---------------------------------------------------------------------------
// Reduce KSPLIT fp16 K-partials; mode 1: add velocity*W_ih^T, ReLU, store g
// (fp32 output) + fp16 copies for decoder (gb) and next step (hout).
// Grid: (4, kB), 256 threads, 4 g's per thread.
// ---------------------------------------------------------------------------
__global__ __launch_bounds__(256)
void k_reduce(const f16_t* __restrict__ part,
              const float* __restrict__ velocity, const float* __restrict__ W_ih,
              float* __restrict__ gout, f16_t* __restrict__ gb,
              f16_t* __restrict__ hout, int t, int mode) {
    const int b = blockIdx.y;
    const int g = blockIdx.x * 1024 + threadIdx.x * 4;

    float v0 = 0.f, v1 = 0.f, v2 = 0.f, v3 = 0.f;
#pragma unroll
    for (int ks = 0; ks < KSPLIT; ks++) {
        f16x4 p = *(const f16x4*)(part + (size_t)ks * ((size_t)kB * kNG) + (size_t)b * kNG + g);
        v0 += (float)p[0]; v1 += (float)p[1]; v2 += (float)p[2]; v3 += (float)p[3];
    }
    if (mode == 1) {
        const float2 vel = *(const float2*)(velocity + ((size_t)t * kB + b) * 2);
        const float4 w01 = *(const float4*)(W_ih + (size_t)g * 2);
        const float4 w23 = *(const float4*)(W_ih + (size_t)g * 2 + 4);
        v0 = fmaxf(0.f, v0 + vel.x * w01.x + vel.y * w01.y);
        v1 = fmaxf(0.f, v1 + vel.x * w01.z + vel.y * w01.w);
        v2 = fmaxf(0.f, v2 + vel.x * w23.x + vel.y * w23.y);
        v3 = fmaxf(0.f, v3 + vel.x * w23.z + vel.y * w23.w);
        float4 o; o.x = v0; o.y = v1; o.z = v2; o.w = v3;
        *(float4*)(gout + ((size_t)t * kB + b) * kNG + g) = o;
    }
    f16x4 h;
    h[0] = (f16_t)v0; h[1] = (f16_t)v1; h[2] = (f16_t)v2; h[3] = (f16_t)v3;
    *(f16x4*)(hout + (size_t)b * kNG + g) = h;
    if (mode == 1 && gb)
        *(f16x4*)(gb + ((size_t)t * kB + b) * kNG + g) = h;
}

// ---------------------------------------------------------------------------
// Decoder (r5 proven form): logits[r][p] = sum_g G[r][g] * Wdec[p][g].
// LDS-staged with XOR swizzle; Gb (fp16 G) if non-null else Gf converted.
// Flat grid 632, XCD-colocated (4 n-tiles of an m-panel per XCD).
// ---------------------------------------------------------------------------
__global__ __launch_bounds__(256)
void k_dec(const float* __restrict__ Gf, const f16_t* __restrict__ Gb,
           const f16_t* __restrict__ Wd, float* __restrict__ out) {
    __shared__ __align__(16) f16_t sA[128 * 64];
    __shared__ __align__(16) f16_t sB[128 * 64];

    const int bid  = blockIdx.x;        // 0..631
    const int xcd  = bid & 7;
    const int idx  = bid >> 3;          // 0..78
    const int tile = xcd * 79 + idx;    // tile = m_t*4 + n_t
    if (tile >= 157 * 4) return;
    const int m0 = (tile >> 2) * 128;
    const int n0 = (tile & 3) * 128;

    const int tid  = threadIdx.x;
    const int lane = tid & 63;
    const int wid  = tid >> 6;
    const int wr   = wid >> 1;
    const int wc   = wid & 1;
    const int M    = kSEQ * kB;   // 20000

    f32x4 acc[4][4];
#pragma unroll
    for (int i = 0; i < 4; i++)
#pragma unroll
        for (int j = 0; j < 4; j++) acc[i][j] = (f32x4){0.f, 0.f, 0.f, 0.f};

    const int sr   = tid >> 1;
    const int half = tid & 1;
    const int sc   = half * 32;
    const unsigned int swzrow = ((unsigned)sr & 7u) << 4;
    const unsigned int sbase  = (unsigned)sr * 128u + (unsigned)half * 64u;
    int arow = m0 + sr; if (arow > M - 1) arow = M - 1;

    for (int k0 = 0; k0 < kNG; k0 += 64) {
        __syncthreads();
        if (Gb) {
            const uint4* gA = (const uint4*)(Gb + (size_t)arow * kNG + k0 + sc);
#pragma unroll
            for (int i = 0; i < 4; i++) {
                unsigned int off = (sbase + (unsigned)i * 16u) ^ swzrow;
                *(uint4*)((char*)sA + off) = gA[i];
            }
        } else {
            const float4* gA = (const float4*)(Gf + (size_t)arow * kNG + k0 + sc);
#pragma unroll
            for (int i = 0; i < 4; i++) {
                float4 a0 = gA[2 * i], a1 = gA[2 * i + 1];
                f16x8 u;
                u[0] = (f16_t)a0.x; u[1] = (f16_t)a0.y; u[2] = (f16_t)a0.z; u[3] = (f16_t)a0.w;
                u[4] = (f16_t)a1.x; u[5] = (f16_t)a1.y; u[6] = (f16_t)a1.z; u[7] = (f16_t)a1.w;
                unsigned int off = (sbase + (unsigned)i * 16u) ^ swzrow;
                *(f16x8*)((char*)sA + off) = u;
            }
        }
        {
            const uint4* gB = (const uint4*)(Wd + (size_t)(n0 + sr) * kNG + k0 + sc);
#pragma unroll
            for (int i = 0; i < 4; i++) {
                unsigned int off = (sbase + (unsigned)i * 16u) ^ swzrow;
                *(uint4*)((char*)sB + off) = gB[i];
            }
        }
        __syncthreads();
#pragma unroll
        for (int ks2 = 0; ks2 < 2; ks2++) {
            f16x8 a[4], b[4];
            const unsigned int klane = (unsigned)(lane >> 4) * 16u + (unsigned)ks2 * 64u;
#pragma unroll
            for (int fm = 0; fm < 4; fm++) {
                const unsigned int row = (unsigned)(wr * 64 + fm * 16 + (lane & 15));
                const unsigned int off = (row * 128u + klane) ^ ((row & 7u) << 4);
                a[fm] = *(const f16x8*)((const char*)sA + off);
            }
#pragma unroll
            for (int fn = 0; fn < 4; fn++) {
                const unsigned int row = (unsigned)(wc * 64 + fn * 16 + (lane & 15));
                const unsigned int off = (row * 128u + klane) ^ ((row & 7u) << 4);
                b[fn] = *(const f16x8*)((const char*)sB + off);
            }
#pragma unroll
            for (int fm = 0; fm < 4; fm++)
#pragma unroll
                for (int fn = 0; fn < 4; fn++)
                    acc[fm][fn] = __builtin_amdgcn_mfma_f32_16x16x32_f16(a[fm], b[fn], acc[fm][fn], 0, 0, 0);
        }
    }

#pragma unroll
    for (int fm = 0; fm < 4; fm++)
#pragma unroll
        for (int fn = 0; fn < 4; fn++) {
            const int row0 = m0 + wr * 64 + fm * 16 + ((lane >> 4) << 2);
            const int col  = n0 + wc * 64 + fn * 16 + (lane & 15);
#pragma unroll
            for (int j = 0; j < 4; j++) {
                const int row = row0 + j;
                if (row < M) out[(size_t)row * kNP + col] = acc[fm][fn][j];
            }
        }
}

// ---------------------------------------------------------------------------
extern "C" void kernel_launch(void* const* d_in, const int* in_sizes, int n_in,
                              void* d_out, int out_size, void* d_ws, size_t ws_size,
                              hipStream_t stream) {
    const float* velocity = (const float*)d_in[0];
    const float* init_pc  = (const float*)d_in[1];
    const float* W_enc    = (const float*)d_in[2];
    const float* W_ih     = (const float*)d_in[3];
    const float* W_hh     = (const float*)d_in[4];
    const float* W_dec    = (const float*)d_in[5];

    float* logits = (float*)d_out;                         // (100,200,512)
    float* gout   = logits + (size_t)kSEQ * kB * kNP;      // (100,200,4096)

    char* ws = (char*)d_ws;
    size_t off = 0;
    auto alloc = [&](size_t bytes) -> void* {
        void* p = ws + off;
        off += (bytes + 255) & ~(size_t)255;
        return p;
    };
    f16_t* whh  = (f16_t*)alloc((size_t)kNG * kNG * 2);
    f16_t* wdec = (f16_t*)alloc((size_t)kNP * kNG * 2);
    f16_t* wenc = (f16_t*)alloc((size_t)kNG * kNP * 2);
    f16_t* ip   = (f16_t*)alloc((size_t)kMP * kNP * 2);
    f16_t* h_buf[2];
    h_buf[0] = (f16_t*)alloc((size_t)kMP * kNG * 2);
    h_buf[1] = (f16_t*)alloc((size_t)kMP * kNG * 2);
    f16_t* partial = (f16_t*)alloc((size_t)KSPLIT * kB * kNG * 2);  // 13.1 MB fp16
    // fp16 copy of g for the decoder (164 MB) — only if ws allows
    f16_t* gb = nullptr;
    if (ws_size >= off + (size_t)kSEQ * kB * kNG * 2 + 4096)
        gb = (f16_t*)alloc((size_t)kSEQ * kB * kNG * 2);

    // zero init_pc pad rows (their partial rows are skipped, but keep clean)
    hipMemsetAsync(ip + (size_t)kB * kNP, 0, (size_t)(kMP - kB) * kNP * 2, stream);

    // --- fp32 -> fp16 conversions ---
    int n8;
    n8 = kNG * kNG / 8;
    k_half<<<(n8 + 255) / 256, 256, 0, stream>>>(W_hh, whh, n8);
    n8 = kNP * kNG / 8;
    k_half<<<(n8 + 255) / 256, 256, 0, stream>>>(W_dec, wdec, n8);
    n8 = kNG * kNP / 8;
    k_half<<<(n8 + 255) / 256, 256, 0, stream>>>(W_enc, wenc, n8);
    n8 = kB * kNP / 8;
    k_half<<<(n8 + 255) / 256, 256, 0, stream>>>(init_pc, ip, n8);

    dim3 gR(4, kB);

    // --- encoder: h0 = init_pc @ W_enc^T ---
    k_gemm_f16<<<512, 256, 0, stream>>>(ip, kNP, wenc, kNP, partial, kNP / KSPLIT);
    k_reduce<<<gR, 256, 0, stream>>>(partial, velocity, W_ih, nullptr, nullptr, h_buf[0], 0, 0);

    // --- recurrent scan ---
    int p = 0;
    for (int t = 0; t < kSEQ; t++) {
        k_gemm_f16<<<512, 256, 0, stream>>>(h_buf[p], kNG, whh, kNG, partial, kNG / KSPLIT);
        k_reduce<<<gR, 256, 0, stream>>>(partial, velocity, W_ih, gout, gb, h_buf[p ^ 1], t, 1);
        p ^= 1;
    }

    // --- decoder ---
    k_dec<<<632, 256, 0, stream>>>(gout, gb, wdec, logits);
}

// Round 10
// 2149.566 us; speedup vs baseline: 1.1387x; 1.1387x over previous
//
#include <hip/hip_runtime.h>
#include <cstdint>
#include <cstddef>

// Problem constants
#define kSEQ 100
#define kB   200
#define kNP  512
#define kNG  4096
#define kMP  256     // padded M for recurrent/encoder GEMMs
#define KSPLIT 8

typedef _Float16 f16_t;
typedef f16_t f16x8 __attribute__((ext_vector_type(8)));
typedef f16_t f16x4 __attribute__((ext_vector_type(4)));
typedef float f32x4 __attribute__((ext_vector_type(4)));

// ---------------------------------------------------------------------------
// Convert fp32 -> fp16 (RTN).  n8 = number of 8-float groups.
// ---------------------------------------------------------------------------
__global__ __launch_bounds__(256)
void k_half(const float* __restrict__ src, f16_t* __restrict__ dst, int n8) {
    int i = blockIdx.x * 256 + threadIdx.x;
    if (i >= n8) return;
    const float4* s = (const float4*)src + (size_t)i * 2;
    float4 v0 = s[0], v1 = s[1];
    f16x8 h;
    h[0] = (f16_t)v0.x; h[1] = (f16_t)v0.y; h[2] = (f16_t)v0.z; h[3] = (f16_t)v0.w;
    h[4] = (f16_t)v1.x; h[5] = (f16_t)v1.y; h[6] = (f16_t)v1.z; h[7] = (f16_t)v1.w;
    *(f16x8*)(dst + (size_t)i * 8) = h;
}

// ---------------------------------------------------------------------------
// Single-product fp16 MFMA GEMM.  r9 structure (XOR-swizzled LDS staging,
// 128x128 tile, fp16 partials / 200-row pitch, XCD-colocated decode) with
// ONE change: 512 threads = 8 waves/block (wave tile 64x32) -> 16 waves/CU
// (4/SIMD) at the same 2 blocks/CU, doubling latency-hiding capacity with
// zero extra memory traffic.
// Grid: flat 512 blocks.
// ---------------------------------------------------------------------------
__global__ __launch_bounds__(512, 4)
void k_gemm_f16(const f16_t* __restrict__ A, int lda,
                const f16_t* __restrict__ B, int ldb,
                f16_t* __restrict__ part, int kPerChunk) {
    __shared__ __align__(16) f16_t sA[128 * 64];
    __shared__ __align__(16) f16_t sB[128 * 64];

    // XCD-colocated decode (blockIdx round-robins over 8 XCDs)
    const int bid    = blockIdx.x;        // 0..511
    const int xcd    = bid & 7;
    const int idx    = bid >> 3;          // 0..63
    const int n_tile = xcd * 4 + (idx & 3);   // 0..31
    const int rem    = idx >> 2;          // 0..15
    const int kc     = rem >> 1;          // 0..7
    const int m_tile = rem & 1;           // 0..1

    const int tid  = threadIdx.x;
    const int lane = tid & 63;
    const int wid  = tid >> 6;   // 0..7
    const int wr   = wid >> 2;   // m-half 0..1 (64 rows)
    const int wc   = wid & 3;    // n-quarter 0..3 (32 cols)
    const int m0   = m_tile * 128;
    const int n0   = n_tile * 128;
    const int kBase = kc * kPerChunk;

    f32x4 acc[4][2];
#pragma unroll
    for (int i = 0; i < 4; i++)
#pragma unroll
        for (int j = 0; j < 2; j++) acc[i][j] = (f32x4){0.f, 0.f, 0.f, 0.f};

    // staging: 1024 16B-chunks (128 rows x 8 chunks); each thread takes 2.
    const int c0   = tid;                 // chunk ids
    const int c1   = tid + 512;
    const int r0s  = c0 >> 3, cc0 = c0 & 7;
    const int r1s  = c1 >> 3, cc1 = c1 & 7;
    const unsigned int off0 = ((unsigned)r0s * 128u + (unsigned)cc0 * 16u) ^ (((unsigned)r0s & 7u) << 4);
    const unsigned int off1 = ((unsigned)r1s * 128u + (unsigned)cc1 * 16u) ^ (((unsigned)r1s & 7u) << 4);

    for (int kb = 0; kb < kPerChunk; kb += 64) {
        const int k0 = kBase + kb;
        __syncthreads();
        {
            const uint4* gA0 = (const uint4*)(A + (size_t)(m0 + r0s) * (size_t)lda + k0 + cc0 * 8);
            const uint4* gA1 = (const uint4*)(A + (size_t)(m0 + r1s) * (size_t)lda + k0 + cc1 * 8);
            const uint4* gB0 = (const uint4*)(B + (size_t)(n0 + r0s) * (size_t)ldb + k0 + cc0 * 8);
            const uint4* gB1 = (const uint4*)(B + (size_t)(n0 + r1s) * (size_t)ldb + k0 + cc1 * 8);
            *(uint4*)((char*)sA + off0) = gA0[0];
            *(uint4*)((char*)sA + off1) = gA1[0];
            *(uint4*)((char*)sB + off0) = gB0[0];
            *(uint4*)((char*)sB + off1) = gB1[0];
        }
        __syncthreads();
#pragma unroll
        for (int ks2 = 0; ks2 < 2; ks2++) {
            f16x8 a[4], b[2];
            const unsigned int klane = (unsigned)(lane >> 4) * 16u + (unsigned)ks2 * 64u;
#pragma unroll
            for (int fm = 0; fm < 4; fm++) {
                const unsigned int row = (unsigned)(wr * 64 + fm * 16 + (lane & 15));
                const unsigned int off = (row * 128u + klane) ^ ((row & 7u) << 4);
                a[fm] = *(const f16x8*)((const char*)sA + off);
            }
#pragma unroll
            for (int fn = 0; fn < 2; fn++) {
                const unsigned int row = (unsigned)(wc * 32 + fn * 16 + (lane & 15));
                const unsigned int off = (row * 128u + klane) ^ ((row & 7u) << 4);
                b[fn] = *(const f16x8*)((const char*)sB + off);
            }
#pragma unroll
            for (int fm = 0; fm < 4; fm++)
#pragma unroll
                for (int fn = 0; fn < 2; fn++)
                    acc[fm][fn] = __builtin_amdgcn_mfma_f32_16x16x32_f16(a[fm], b[fn], acc[fm][fn], 0, 0, 0);
        }
    }

    // fp16 partial, 200-row pitch, rows >= kB skipped
    f16_t* po = part + (size_t)kc * ((size_t)kB * kNG);
#pragma unroll
    for (int fm = 0; fm < 4; fm++)
#pragma unroll
        for (int fn = 0; fn < 2; fn++) {
            const int row0 = m0 + wr * 64 + fm * 16 + ((lane >> 4) << 2);
            const int col  = n0 + wc * 32 + fn * 16 + (lane & 15);
#pragma unroll
            for (int j = 0; j < 4; j++) {
                const int row = row0 + j;
                if (row < kB)
                    po[(size_t)row * kNG + col] = (f16_t)acc[fm][fn][j];
            }
        }
}

// ---------------------------------------------------------------------------
// Reduce KSPLIT fp16 K-partials; mode 1: add velocity*W_ih^T, ReLU, store g
// (fp32 output) + fp16 copies for decoder (gb) and next step (hout).
// Grid: (4, kB), 256 threads, 4 g's per thread.
// ---------------------------------------------------------------------------
__global__ __launch_bounds__(256)
void k_reduce(const f16_t* __restrict__ part,
              const float* __restrict__ velocity, const float* __restrict__ W_ih,
              float* __restrict__ gout, f16_t* __restrict__ gb,
              f16_t* __restrict__ hout, int t, int mode) {
    const int b = blockIdx.y;
    const int g = blockIdx.x * 1024 + threadIdx.x * 4;

    float v0 = 0.f, v1 = 0.f, v2 = 0.f, v3 = 0.f;
#pragma unroll
    for (int ks = 0; ks < KSPLIT; ks++) {
        f16x4 p = *(const f16x4*)(part + (size_t)ks * ((size_t)kB * kNG) + (size_t)b * kNG + g);
        v0 += (float)p[0]; v1 += (float)p[1]; v2 += (float)p[2]; v3 += (float)p[3];
    }
    if (mode == 1) {
        const float2 vel = *(const float2*)(velocity + ((size_t)t * kB + b) * 2);
        const float4 w01 = *(const float4*)(W_ih + (size_t)g * 2);
        const float4 w23 = *(const float4*)(W_ih + (size_t)g * 2 + 4);
        v0 = fmaxf(0.f, v0 + vel.x * w01.x + vel.y * w01.y);
        v1 = fmaxf(0.f, v1 + vel.x * w01.z + vel.y * w01.w);
        v2 = fmaxf(0.f, v2 + vel.x * w23.x + vel.y * w23.y);
        v3 = fmaxf(0.f, v3 + vel.x * w23.z + vel.y * w23.w);
        float4 o; o.x = v0; o.y = v1; o.z = v2; o.w = v3;
        *(float4*)(gout + ((size_t)t * kB + b) * kNG + g) = o;
    }
    f16x4 h;
    h[0] = (f16_t)v0; h[1] = (f16_t)v1; h[2] = (f16_t)v2; h[3] = (f16_t)v3;
    *(f16x4*)(hout + (size_t)b * kNG + g) = h;
    if (mode == 1 && gb)
        *(f16x4*)(gb + ((size_t)t * kB + b) * kNG + g) = h;
}

// ---------------------------------------------------------------------------
// Decoder (r5 proven form): logits[r][p] = sum_g G[r][g] * Wdec[p][g].
// LDS-staged with XOR swizzle; Gb (fp16 G) if non-null else Gf converted.
// Flat grid 632, XCD-colocated (4 n-tiles of an m-panel per XCD).
// ---------------------------------------------------------------------------
__global__ __launch_bounds__(256)
void k_dec(const float* __restrict__ Gf, const f16_t* __restrict__ Gb,
           const f16_t* __restrict__ Wd, float* __restrict__ out) {
    __shared__ __align__(16) f16_t sA[128 * 64];
    __shared__ __align__(16) f16_t sB[128 * 64];

    const int bid  = blockIdx.x;        // 0..631
    const int xcd  = bid & 7;
    const int idx  = bid >> 3;          // 0..78
    const int tile = xcd * 79 + idx;    // tile = m_t*4 + n_t
    if (tile >= 157 * 4) return;
    const int m0 = (tile >> 2) * 128;
    const int n0 = (tile & 3) * 128;

    const int tid  = threadIdx.x;
    const int lane = tid & 63;
    const int wid  = tid >> 6;
    const int wr   = wid >> 1;
    const int wc   = wid & 1;
    const int M    = kSEQ * kB;   // 20000

    f32x4 acc[4][4];
#pragma unroll
    for (int i = 0; i < 4; i++)
#pragma unroll
        for (int j = 0; j < 4; j++) acc[i][j] = (f32x4){0.f, 0.f, 0.f, 0.f};

    const int sr   = tid >> 1;
    const int half = tid & 1;
    const int sc   = half * 32;
    const unsigned int swzrow = ((unsigned)sr & 7u) << 4;
    const unsigned int sbase  = (unsigned)sr * 128u + (unsigned)half * 64u;
    int arow = m0 + sr; if (arow > M - 1) arow = M - 1;

    for (int k0 = 0; k0 < kNG; k0 += 64) {
        __syncthreads();
        if (Gb) {
            const uint4* gA = (const uint4*)(Gb + (size_t)arow * kNG + k0 + sc);
#pragma unroll
            for (int i = 0; i < 4; i++) {
                unsigned int off = (sbase + (unsigned)i * 16u) ^ swzrow;
                *(uint4*)((char*)sA + off) = gA[i];
            }
        } else {
            const float4* gA = (const float4*)(Gf + (size_t)arow * kNG + k0 + sc);
#pragma unroll
            for (int i = 0; i < 4; i++) {
                float4 a0 = gA[2 * i], a1 = gA[2 * i + 1];
                f16x8 u;
                u[0] = (f16_t)a0.x; u[1] = (f16_t)a0.y; u[2] = (f16_t)a0.z; u[3] = (f16_t)a0.w;
                u[4] = (f16_t)a1.x; u[5] = (f16_t)a1.y; u[6] = (f16_t)a1.z; u[7] = (f16_t)a1.w;
                unsigned int off = (sbase + (unsigned)i * 16u) ^ swzrow;
                *(f16x8*)((char*)sA + off) = u;
            }
        }
        {
            const uint4* gB = (const uint4*)(Wd + (size_t)(n0 + sr) * kNG + k0 + sc);
#pragma unroll
            for (int i = 0; i < 4; i++) {
                unsigned int off = (sbase + (unsigned)i * 16u) ^ swzrow;
                *(uint4*)((char*)sB + off) = gB[i];
            }
        }
        __syncthreads();
#pragma unroll
        for (int ks2 = 0; ks2 < 2; ks2++) {
            f16x8 a[4], b[4];
            const unsigned int klane = (unsigned)(lane >> 4) * 16u + (unsigned)ks2 * 64u;
#pragma unroll
            for (int fm = 0; fm < 4; fm++) {
                const unsigned int row = (unsigned)(wr * 64 + fm * 16 + (lane & 15));
                const unsigned int off = (row * 128u + klane) ^ ((row & 7u) << 4);
                a[fm] = *(const f16x8*)((const char*)sA + off);
            }
#pragma unroll
            for (int fn = 0; fn < 4; fn++) {
                const unsigned int row = (unsigned)(wc * 64 + fn * 16 + (lane & 15));
                const unsigned int off = (row * 128u + klane) ^ ((row & 7u) << 4);
                b[fn] = *(const f16x8*)((const char*)sB + off);
            }
#pragma unroll
            for (int fm = 0; fm < 4; fm++)
#pragma unroll
                for (int fn = 0; fn < 4; fn++)
                    acc[fm][fn] = __builtin_amdgcn_mfma_f32_16x16x32_f16(a[fm], b[fn], acc[fm][fn], 0, 0, 0);
        }
    }

#pragma unroll
    for (int fm = 0; fm < 4; fm++)
#pragma unroll
        for (int fn = 0; fn < 4; fn++) {
            const int row0 = m0 + wr * 64 + fm * 16 + ((lane >> 4) << 2);
            const int col  = n0 + wc * 64 + fn * 16 + (lane & 15);
#pragma unroll
            for (int j = 0; j < 4; j++) {
                const int row = row0 + j;
                if (row < M) out[(size_t)row * kNP + col] = acc[fm][fn][j];
            }
        }
}

// ---------------------------------------------------------------------------
extern "C" void kernel_launch(void* const* d_in, const int* in_sizes, int n_in,
                              void* d_out, int out_size, void* d_ws, size_t ws_size,
                              hipStream_t stream) {
    const float* velocity = (const float*)d_in[0];
    const float* init_pc  = (const float*)d_in[1];
    const float* W_enc    = (const float*)d_in[2];
    const float* W_ih     = (const float*)d_in[3];
    const float* W_hh     = (const float*)d_in[4];
    const float* W_dec    = (const float*)d_in[5];

    float* logits = (float*)d_out;                         // (100,200,512)
    float* gout   = logits + (size_t)kSEQ * kB * kNP;      // (100,200,4096)

    char* ws = (char*)d_ws;
    size_t off = 0;
    auto alloc = [&](size_t bytes) -> void* {
        void* p = ws + off;
        off += (bytes + 255) & ~(size_t)255;
        return p;
    };
    f16_t* whh  = (f16_t*)alloc((size_t)kNG * kNG * 2);
    f16_t* wdec = (f16_t*)alloc((size_t)kNP * kNG * 2);
    f16_t* wenc = (f16_t*)alloc((size_t)kNG * kNP * 2);
    f16_t* ip   = (f16_t*)alloc((size_t)kMP * kNP * 2);
    f16_t* h_buf[2];
    h_buf[0] = (f16_t*)alloc((size_t)kMP * kNG * 2);
    h_buf[1] = (f16_t*)alloc((size_t)kMP * kNG * 2);
    f16_t* partial = (f16_t*)alloc((size_t)KSPLIT * kB * kNG * 2);  // 13.1 MB fp16
    // fp16 copy of g for the decoder (164 MB) — only if ws allows
    f16_t* gb = nullptr;
    if (ws_size >= off + (size_t)kSEQ * kB * kNG * 2 + 4096)
        gb = (f16_t*)alloc((size_t)kSEQ * kB * kNG * 2);

    // zero init_pc pad rows (their partial rows are skipped, but keep clean)
    hipMemsetAsync(ip + (size_t)kB * kNP, 0, (size_t)(kMP - kB) * kNP * 2, stream);

    // --- fp32 -> fp16 conversions ---
    int n8;
    n8 = kNG * kNG / 8;
    k_half<<<(n8 + 255) / 256, 256, 0, stream>>>(W_hh, whh, n8);
    n8 = kNP * kNG / 8;
    k_half<<<(n8 + 255) / 256, 256, 0, stream>>>(W_dec, wdec, n8);
    n8 = kNG * kNP / 8;
    k_half<<<(n8 + 255) / 256, 256, 0, stream>>>(W_enc, wenc, n8);
    n8 = kB * kNP / 8;
    k_half<<<(n8 + 255) / 256, 256, 0, stream>>>(init_pc, ip, n8);

    dim3 gR(4, kB);

    // --- encoder: h0 = init_pc @ W_enc^T ---
    k_gemm_f16<<<512, 512, 0, stream>>>(ip, kNP, wenc, kNP, partial, kNP / KSPLIT);
    k_reduce<<<gR, 256, 0, stream>>>(partial, velocity, W_ih, nullptr, nullptr, h_buf[0], 0, 0);

    // --- recurrent scan ---
    int p = 0;
    for (int t = 0; t < kSEQ; t++) {
        k_gemm_f16<<<512, 512, 0, stream>>>(h_buf[p], kNG, whh, kNG, partial, kNG / KSPLIT);
        k_reduce<<<gR, 256, 0, stream>>>(partial, velocity, W_ih, gout, gb, h_buf[p ^ 1], t, 1);
        p ^= 1;
    }

    // --- decoder ---
    k_dec<<<632, 256, 0, stream>>>(gout, gb, wdec, logits);
}

// Round 11
// 2089.337 us; speedup vs baseline: 1.1715x; 1.0288x over previous
//
#include <hip/hip_runtime.h>
#include <cstdint>
#include <cstddef>

// Problem constants
#define kSEQ 100
#define kB   200
#define kNP  512
#define kNG  4096
#define kMP  256     // padded M for recurrent/encoder GEMMs
#define KSPLIT 8

typedef _Float16 f16_t;
typedef f16_t f16x8 __attribute__((ext_vector_type(8)));
typedef f16_t f16x4 __attribute__((ext_vector_type(4)));
typedef float f32x4 __attribute__((ext_vector_type(4)));

__device__ __forceinline__ void gld_lds16(const f16_t* g, f16_t* l) {
    __builtin_amdgcn_global_load_lds(
        (const __attribute__((address_space(1))) unsigned int*)g,
        (__attribute__((address_space(3))) unsigned int*)l, 16, 0, 0);
}

// ---------------------------------------------------------------------------
// Convert fp32 -> fp16 (RTN).  n8 = number of 8-float groups.
// ---------------------------------------------------------------------------
__global__ __launch_bounds__(256)
void k_half(const float* __restrict__ src, f16_t* __restrict__ dst, int n8) {
    int i = blockIdx.x * 256 + threadIdx.x;
    if (i >= n8) return;
    const float4* s = (const float4*)src + (size_t)i * 2;
    float4 v0 = s[0], v1 = s[1];
    f16x8 h;
    h[0] = (f16_t)v0.x; h[1] = (f16_t)v0.y; h[2] = (f16_t)v0.z; h[3] = (f16_t)v0.w;
    h[4] = (f16_t)v1.x; h[5] = (f16_t)v1.y; h[6] = (f16_t)v1.z; h[7] = (f16_t)v1.w;
    *(f16x8*)(dst + (size_t)i * 8) = h;
}

// ---------------------------------------------------------------------------
// Single-product fp16 MFMA GEMM (r10 structure: 512 thr / 8 waves, 128x128
// tile, fp16 partials 200-row pitch, XCD-colocated decode).  ONE perf change:
// staging via global_load_lds width-16 (direct HBM/L2 -> LDS, no VGPR
// roundtrip).  LDS layout stays LINEAR; the XOR swizzle is applied to the
// per-lane GLOBAL chunk index (rule: linear dest + inverse-swz source + swz
// read).  Read side is byte-identical to r10.
// Grid: flat 512 blocks.
// ---------------------------------------------------------------------------
__global__ __launch_bounds__(512, 4)
void k_gemm_f16(const f16_t* __restrict__ A, int lda,
                const f16_t* __restrict__ B, int ldb,
                f16_t* __restrict__ part, int kPerChunk) {
    __shared__ __align__(16) f16_t sA[128 * 64];
    __shared__ __align__(16) f16_t sB[128 * 64];

    // XCD-colocated decode (blockIdx round-robins over 8 XCDs)
    const int bid    = blockIdx.x;        // 0..511
    const int xcd    = bid & 7;
    const int idx    = bid >> 3;          // 0..63
    const int n_tile = xcd * 4 + (idx & 3);   // 0..31
    const int rem    = idx >> 2;          // 0..15
    const int kc     = rem >> 1;          // 0..7
    const int m_tile = rem & 1;           // 0..1

    const int tid  = threadIdx.x;
    const int lane = tid & 63;
    const int wid  = tid >> 6;   // 0..7
    const int wr   = wid >> 2;   // m-half 0..1 (64 rows)
    const int wc   = wid & 3;    // n-quarter 0..3 (32 cols)
    const int m0   = m_tile * 128;
    const int n0   = n_tile * 128;
    const int kBase = kc * kPerChunk;

    f32x4 acc[4][2];
#pragma unroll
    for (int i = 0; i < 4; i++)
#pragma unroll
        for (int j = 0; j < 2; j++) acc[i][j] = (f32x4){0.f, 0.f, 0.f, 0.f};

    // staging: 1024 linear 16B slots per array; wave w owns slots
    // [w*128, w*128+127] in 2 issues of 64 lanes.  Slot s holds global
    // chunk (row = s>>3, c = (s&7) ^ (row&7))  -> read-side XOR matches.
    const int s0   = wid * 128 + lane;
    const int s1   = s0 + 64;
    const int r0s  = s0 >> 3, c0 = (s0 & 7) ^ (r0s & 7);
    const int r1s  = s1 >> 3, c1 = (s1 & 7) ^ (r1s & 7);
    f16_t* dA0 = sA + (size_t)(wid * 128) * 8;
    f16_t* dA1 = sA + (size_t)(wid * 128 + 64) * 8;
    f16_t* dB0 = sB + (size_t)(wid * 128) * 8;
    f16_t* dB1 = sB + (size_t)(wid * 128 + 64) * 8;

    for (int kb = 0; kb < kPerChunk; kb += 64) {
        const int k0 = kBase + kb;
        __syncthreads();
        gld_lds16(A + (size_t)(m0 + r0s) * (size_t)lda + k0 + c0 * 8, dA0);
        gld_lds16(A + (size_t)(m0 + r1s) * (size_t)lda + k0 + c1 * 8, dA1);
        gld_lds16(B + (size_t)(n0 + r0s) * (size_t)ldb + k0 + c0 * 8, dB0);
        gld_lds16(B + (size_t)(n0 + r1s) * (size_t)ldb + k0 + c1 * 8, dB1);
        __syncthreads();
#pragma unroll
        for (int ks2 = 0; ks2 < 2; ks2++) {
            f16x8 a[4], b[2];
            const unsigned int klane = (unsigned)(lane >> 4) * 16u + (unsigned)ks2 * 64u;
#pragma unroll
            for (int fm = 0; fm < 4; fm++) {
                const unsigned int row = (unsigned)(wr * 64 + fm * 16 + (lane & 15));
                const unsigned int off = (row * 128u + klane) ^ ((row & 7u) << 4);
                a[fm] = *(const f16x8*)((const char*)sA + off);
            }
#pragma unroll
            for (int fn = 0; fn < 2; fn++) {
                const unsigned int row = (unsigned)(wc * 32 + fn * 16 + (lane & 15));
                const unsigned int off = (row * 128u + klane) ^ ((row & 7u) << 4);
                b[fn] = *(const f16x8*)((const char*)sB + off);
            }
#pragma unroll
            for (int fm = 0; fm < 4; fm++)
#pragma unroll
                for (int fn = 0; fn < 2; fn++)
                    acc[fm][fn] = __builtin_amdgcn_mfma_f32_16x16x32_f16(a[fm], b[fn], acc[fm][fn], 0, 0, 0);
        }
    }

    // fp16 partial, 200-row pitch, rows >= kB skipped
    f16_t* po = part + (size_t)kc * ((size_t)kB * kNG);
#pragma unroll
    for (int fm = 0; fm < 4; fm++)
#pragma unroll
        for (int fn = 0; fn < 2; fn++) {
            const int row0 = m0 + wr * 64 + fm * 16 + ((lane >> 4) << 2);
            const int col  = n0 + wc * 32 + fn * 16 + (lane & 15);
#pragma unroll
            for (int j = 0; j < 4; j++) {
                const int row = row0 + j;
                if (row < kB)
                    po[(size_t)row * kNG + col] = (f16_t)acc[fm][fn][j];
            }
        }
}

// ---------------------------------------------------------------------------
// Reduce KSPLIT fp16 K-partials; mode 1: add velocity*W_ih^T, ReLU, store g
// (fp32 output) + fp16 g into gb[t] (which doubles as next step's A).
// mode 0 (encoder): write h0 to hout.  Grid: (4, kB), 256 thr, 4 g's/thread.
// ---------------------------------------------------------------------------
__global__ __launch_bounds__(256)
void k_reduce(const f16_t* __restrict__ part,
              const float* __restrict__ velocity, const float* __restrict__ W_ih,
              float* __restrict__ gout, f16_t* __restrict__ gb,
              f16_t* __restrict__ hout, int t, int mode) {
    const int b = blockIdx.y;
    const int g = blockIdx.x * 1024 + threadIdx.x * 4;

    float v0 = 0.f, v1 = 0.f, v2 = 0.f, v3 = 0.f;
#pragma unroll
    for (int ks = 0; ks < KSPLIT; ks++) {
        f16x4 p = *(const f16x4*)(part + (size_t)ks * ((size_t)kB * kNG) + (size_t)b * kNG + g);
        v0 += (float)p[0]; v1 += (float)p[1]; v2 += (float)p[2]; v3 += (float)p[3];
    }
    if (mode == 1) {
        const float2 vel = *(const float2*)(velocity + ((size_t)t * kB + b) * 2);
        const float4 w01 = *(const float4*)(W_ih + (size_t)g * 2);
        const float4 w23 = *(const float4*)(W_ih + (size_t)g * 2 + 4);
        v0 = fmaxf(0.f, v0 + vel.x * w01.x + vel.y * w01.y);
        v1 = fmaxf(0.f, v1 + vel.x * w01.z + vel.y * w01.w);
        v2 = fmaxf(0.f, v2 + vel.x * w23.x + vel.y * w23.y);
        v3 = fmaxf(0.f, v3 + vel.x * w23.z + vel.y * w23.w);
        float4 o; o.x = v0; o.y = v1; o.z = v2; o.w = v3;
        *(float4*)(gout + ((size_t)t * kB + b) * kNG + g) = o;
    }
    f16x4 h;
    h[0] = (f16_t)v0; h[1] = (f16_t)v1; h[2] = (f16_t)v2; h[3] = (f16_t)v3;
    if (hout)
        *(f16x4*)(hout + (size_t)b * kNG + g) = h;
    if (mode == 1 && gb)
        *(f16x4*)(gb + ((size_t)t * kB + b) * kNG + g) = h;
}

// ---------------------------------------------------------------------------
// Decoder (r5 proven form): logits[r][p] = sum_g G[r][g] * Wdec[p][g].
// LDS-staged with XOR swizzle; Gb (fp16 G) if non-null else Gf converted.
// Flat grid 632, XCD-colocated (4 n-tiles of an m-panel per XCD).
// ---------------------------------------------------------------------------
__global__ __launch_bounds__(256)
void k_dec(const float* __restrict__ Gf, const f16_t* __restrict__ Gb,
           const f16_t* __restrict__ Wd, float* __restrict__ out) {
    __shared__ __align__(16) f16_t sA[128 * 64];
    __shared__ __align__(16) f16_t sB[128 * 64];

    const int bid  = blockIdx.x;        // 0..631
    const int xcd  = bid & 7;
    const int idx  = bid >> 3;          // 0..78
    const int tile = xcd * 79 + idx;    // tile = m_t*4 + n_t
    if (tile >= 157 * 4) return;
    const int m0 = (tile >> 2) * 128;
    const int n0 = (tile & 3) * 128;

    const int tid  = threadIdx.x;
    const int lane = tid & 63;
    const int wid  = tid >> 6;
    const int wr   = wid >> 1;
    const int wc   = wid & 1;
    const int M    = kSEQ * kB;   // 20000

    f32x4 acc[4][4];
#pragma unroll
    for (int i = 0; i < 4; i++)
#pragma unroll
        for (int j = 0; j < 4; j++) acc[i][j] = (f32x4){0.f, 0.f, 0.f, 0.f};

    const int sr   = tid >> 1;
    const int half = tid & 1;
    const int sc   = half * 32;
    const unsigned int swzrow = ((unsigned)sr & 7u) << 4;
    const unsigned int sbase  = (unsigned)sr * 128u + (unsigned)half * 64u;
    int arow = m0 + sr; if (arow > M - 1) arow = M - 1;

    for (int k0 = 0; k0 < kNG; k0 += 64) {
        __syncthreads();
        if (Gb) {
            const uint4* gA = (const uint4*)(Gb + (size_t)arow * kNG + k0 + sc);
#pragma unroll
            for (int i = 0; i < 4; i++) {
                unsigned int off = (sbase + (unsigned)i * 16u) ^ swzrow;
                *(uint4*)((char*)sA + off) = gA[i];
            }
        } else {
            const float4* gA = (const float4*)(Gf + (size_t)arow * kNG + k0 + sc);
#pragma unroll
            for (int i = 0; i < 4; i++) {
                float4 a0 = gA[2 * i], a1 = gA[2 * i + 1];
                f16x8 u;
                u[0] = (f16_t)a0.x; u[1] = (f16_t)a0.y; u[2] = (f16_t)a0.z; u[3] = (f16_t)a0.w;
                u[4] = (f16_t)a1.x; u[5] = (f16_t)a1.y; u[6] = (f16_t)a1.z; u[7] = (f16_t)a1.w;
                unsigned int off = (sbase + (unsigned)i * 16u) ^ swzrow;
                *(f16x8*)((char*)sA + off) = u;
            }
        }
        {
            const uint4* gB = (const uint4*)(Wd + (size_t)(n0 + sr) * kNG + k0 + sc);
#pragma unroll
            for (int i = 0; i < 4; i++) {
                unsigned int off = (sbase + (unsigned)i * 16u) ^ swzrow;
                *(uint4*)((char*)sB + off) = gB[i];
            }
        }
        __syncthreads();
#pragma unroll
        for (int ks2 = 0; ks2 < 2; ks2++) {
            f16x8 a[4], b[4];
            const unsigned int klane = (unsigned)(lane >> 4) * 16u + (unsigned)ks2 * 64u;
#pragma unroll
            for (int fm = 0; fm < 4; fm++) {
                const unsigned int row = (unsigned)(wr * 64 + fm * 16 + (lane & 15));
                const unsigned int off = (row * 128u + klane) ^ ((row & 7u) << 4);
                a[fm] = *(const f16x8*)((const char*)sA + off);
            }
#pragma unroll
            for (int fn = 0; fn < 4; fn++) {
                const unsigned int row = (unsigned)(wc * 64 + fn * 16 + (lane & 15));
                const unsigned int off = (row * 128u + klane) ^ ((row & 7u) << 4);
                b[fn] = *(const f16x8*)((const char*)sB + off);
            }
#pragma unroll
            for (int fm = 0; fm < 4; fm++)
#pragma unroll
                for (int fn = 0; fn < 4; fn++)
                    acc[fm][fn] = __builtin_amdgcn_mfma_f32_16x16x32_f16(a[fm], b[fn], acc[fm][fn], 0, 0, 0);
        }
    }

#pragma unroll
    for (int fm = 0; fm < 4; fm++)
#pragma unroll
        for (int fn = 0; fn < 4; fn++) {
            const int row0 = m0 + wr * 64 + fm * 16 + ((lane >> 4) << 2);
            const int col  = n0 + wc * 64 + fn * 16 + (lane & 15);
#pragma unroll
            for (int j = 0; j < 4; j++) {
                const int row = row0 + j;
                if (row < M) out[(size_t)row * kNP + col] = acc[fm][fn][j];
            }
        }
}

// ---------------------------------------------------------------------------
extern "C" void kernel_launch(void* const* d_in, const int* in_sizes, int n_in,
                              void* d_out, int out_size, void* d_ws, size_t ws_size,
                              hipStream_t stream) {
    const float* velocity = (const float*)d_in[0];
    const float* init_pc  = (const float*)d_in[1];
    const float* W_enc    = (const float*)d_in[2];
    const float* W_ih     = (const float*)d_in[3];
    const float* W_hh     = (const float*)d_in[4];
    const float* W_dec    = (const float*)d_in[5];

    float* logits = (float*)d_out;                         // (100,200,512)
    float* gout   = logits + (size_t)kSEQ * kB * kNP;      // (100,200,4096)

    char* ws = (char*)d_ws;
    size_t off = 0;
    auto alloc = [&](size_t bytes) -> void* {
        void* p = ws + off;
        off += (bytes + 255) & ~(size_t)255;
        return p;
    };
    f16_t* whh  = (f16_t*)alloc((size_t)kNG * kNG * 2);
    f16_t* wdec = (f16_t*)alloc((size_t)kNP * kNG * 2);
    f16_t* wenc = (f16_t*)alloc((size_t)kNG * kNP * 2);
    f16_t* ip   = (f16_t*)alloc((size_t)kMP * kNP * 2);
    f16_t* h_buf[2];
    h_buf[0] = (f16_t*)alloc((size_t)kMP * kNG * 2);
    h_buf[1] = (f16_t*)alloc((size_t)kMP * kNG * 2);
    f16_t* partial = (f16_t*)alloc((size_t)KSPLIT * kB * kNG * 2);  // 13.1 MB fp16
    // fp16 g (doubles as the scan's h chain); +kMP rows pad for t=99 A-reads
    f16_t* gb = nullptr;
    if (ws_size >= off + ((size_t)kSEQ * kB + kMP) * kNG * 2 + 4096)
        gb = (f16_t*)alloc(((size_t)kSEQ * kB + kMP) * kNG * 2);

    // zero init_pc pad rows
    hipMemsetAsync(ip + (size_t)kB * kNP, 0, (size_t)(kMP - kB) * kNP * 2, stream);

    // --- fp32 -> fp16 conversions ---
    int n8;
    n8 = kNG * kNG / 8;
    k_half<<<(n8 + 255) / 256, 256, 0, stream>>>(W_hh, whh, n8);
    n8 = kNP * kNG / 8;
    k_half<<<(n8 + 255) / 256, 256, 0, stream>>>(W_dec, wdec, n8);
    n8 = kNG * kNP / 8;
    k_half<<<(n8 + 255) / 256, 256, 0, stream>>>(W_enc, wenc, n8);
    n8 = kB * kNP / 8;
    k_half<<<(n8 + 255) / 256, 256, 0, stream>>>(init_pc, ip, n8);

    dim3 gR(4, kB);

    // --- encoder: h0 = init_pc @ W_enc^T ---
    k_gemm_f16<<<512, 512, 0, stream>>>(ip, kNP, wenc, kNP, partial, kNP / KSPLIT);
    k_reduce<<<gR, 256, 0, stream>>>(partial, velocity, W_ih, nullptr, nullptr, h_buf[0], 0, 0);

    // --- recurrent scan (h chain lives inside gb when available) ---
    if (gb) {
        const f16_t* Acur = h_buf[0];
        for (int t = 0; t < kSEQ; t++) {
            k_gemm_f16<<<512, 512, 0, stream>>>(Acur, kNG, whh, kNG, partial, kNG / KSPLIT);
            k_reduce<<<gR, 256, 0, stream>>>(partial, velocity, W_ih, gout, gb, nullptr, t, 1);
            Acur = gb + (size_t)t * kB * kNG;
        }
    } else {
        int p = 0;
        for (int t = 0; t < kSEQ; t++) {
            k_gemm_f16<<<512, 512, 0, stream>>>(h_buf[p], kNG, whh, kNG, partial, kNG / KSPLIT);
            k_reduce<<<gR, 256, 0, stream>>>(partial, velocity, W_ih, gout, nullptr, h_buf[p ^ 1], t, 1);
            p ^= 1;
        }
    }

    // --- decoder ---
    k_dec<<<632, 256, 0, stream>>>(gout, gb, wdec, logits);
}

// Round 12
// 2074.477 us; speedup vs baseline: 1.1799x; 1.0072x over previous
//
#include <hip/hip_runtime.h>
#include <cstdint>
#include <cstddef>

// Problem constants
#define kSEQ 100
#define kB   200
#define kNP  512
#define kNG  4096
#define kMP  256     // padded M for recurrent/encoder GEMMs
#define KSPLIT 8

typedef _Float16 f16_t;
typedef f16_t f16x8 __attribute__((ext_vector_type(8)));
typedef f16_t f16x4 __attribute__((ext_vector_type(4)));
typedef float f32x4 __attribute__((ext_vector_type(4)));

__device__ __forceinline__ void gld_lds16(const f16_t* g, f16_t* l) {
    __builtin_amdgcn_global_load_lds(
        (const __attribute__((address_space(1))) unsigned int*)g,
        (__attribute__((address_space(3))) unsigned int*)l, 16, 0, 0);
}

// ---------------------------------------------------------------------------
// Convert fp32 -> fp16 (RTN).  n8 = number of 8-float groups.
// ---------------------------------------------------------------------------
__global__ __launch_bounds__(256)
void k_half(const float* __restrict__ src, f16_t* __restrict__ dst, int n8) {
    int i = blockIdx.x * 256 + threadIdx.x;
    if (i >= n8) return;
    const float4* s = (const float4*)src + (size_t)i * 2;
    float4 v0 = s[0], v1 = s[1];
    f16x8 h;
    h[0] = (f16_t)v0.x; h[1] = (f16_t)v0.y; h[2] = (f16_t)v0.z; h[3] = (f16_t)v0.w;
    h[4] = (f16_t)v1.x; h[5] = (f16_t)v1.y; h[6] = (f16_t)v1.z; h[7] = (f16_t)v1.w;
    *(f16x8*)(dst + (size_t)i * 8) = h;
}

// ---------------------------------------------------------------------------
// Single-product fp16 MFMA GEMM (r11 structure: 512 thr / 8 waves, 128x128
// tile, global_load_lds staging w/ source-side swizzle, fp16 partials,
// XCD-colocated decode).  ONE change: DOUBLE-BUFFERED LDS — next K-tile's
// loads are issued BEFORE computing the current tile, so the barrier's
// vmcnt(0) drain finds them already complete (T3 2-phase recipe).
// Grid: flat 512 blocks -> 2 blocks/CU (LDS 64 KB).
// ---------------------------------------------------------------------------
__global__ __launch_bounds__(512, 4)
void k_gemm_f16(const f16_t* __restrict__ A, int lda,
                const f16_t* __restrict__ B, int ldb,
                f16_t* __restrict__ part, int kPerChunk) {
    __shared__ __align__(16) f16_t sA[2][128 * 64];
    __shared__ __align__(16) f16_t sB[2][128 * 64];

    // XCD-colocated decode (blockIdx round-robins over 8 XCDs)
    const int bid    = blockIdx.x;        // 0..511
    const int xcd    = bid & 7;
    const int idx    = bid >> 3;          // 0..63
    const int n_tile = xcd * 4 + (idx & 3);   // 0..31
    const int rem    = idx >> 2;          // 0..15
    const int kc     = rem >> 1;          // 0..7
    const int m_tile = rem & 1;           // 0..1

    const int tid  = threadIdx.x;
    const int lane = tid & 63;
    const int wid  = tid >> 6;   // 0..7
    const int wr   = wid >> 2;   // m-half 0..1 (64 rows)
    const int wc   = wid & 3;    // n-quarter 0..3 (32 cols)
    const int m0   = m_tile * 128;
    const int n0   = n_tile * 128;
    const int kBase = kc * kPerChunk;
    const int nIter = kPerChunk >> 6;

    f32x4 acc[4][2];
#pragma unroll
    for (int i = 0; i < 4; i++)
#pragma unroll
        for (int j = 0; j < 2; j++) acc[i][j] = (f32x4){0.f, 0.f, 0.f, 0.f};

    // staging: 1024 linear 16B slots per array; wave w owns slots
    // [w*128, w*128+127] in 2 issues of 64 lanes.  Slot s holds global
    // chunk (row = s>>3, c = (s&7) ^ (row&7))  -> read-side XOR matches.
    const int s0   = wid * 128 + lane;
    const int s1   = s0 + 64;
    const int r0s  = s0 >> 3, c0 = (s0 & 7) ^ (r0s & 7);
    const int r1s  = s1 >> 3, c1 = (s1 & 7) ^ (r1s & 7);
    const int b0   = (wid * 128) * 8;        // wave-uniform LDS elem offsets
    const int b1   = (wid * 128 + 64) * 8;

    const f16_t* gA0 = A + (size_t)(m0 + r0s) * (size_t)lda + c0 * 8;
    const f16_t* gA1 = A + (size_t)(m0 + r1s) * (size_t)lda + c1 * 8;
    const f16_t* gB0 = B + (size_t)(n0 + r0s) * (size_t)ldb + c0 * 8;
    const f16_t* gB1 = B + (size_t)(n0 + r1s) * (size_t)ldb + c1 * 8;

    // prologue: stage K-tile 0 into buf 0
    gld_lds16(gA0 + kBase, &sA[0][b0]);
    gld_lds16(gA1 + kBase, &sA[0][b1]);
    gld_lds16(gB0 + kBase, &sB[0][b0]);
    gld_lds16(gB1 + kBase, &sB[0][b1]);
    __syncthreads();

    int cur = 0;
    for (int kb = 0; kb < nIter; ++kb) {
        // prefetch next K-tile into the other buffer (in flight during MFMA)
        if (kb + 1 < nIter) {
            const int kn = kBase + (kb + 1) * 64;
            gld_lds16(gA0 + kn, &sA[cur ^ 1][b0]);
            gld_lds16(gA1 + kn, &sA[cur ^ 1][b1]);
            gld_lds16(gB0 + kn, &sB[cur ^ 1][b0]);
            gld_lds16(gB1 + kn, &sB[cur ^ 1][b1]);
        }
        const f16_t* cA = sA[cur];
        const f16_t* cB = sB[cur];
#pragma unroll
        for (int ks2 = 0; ks2 < 2; ks2++) {
            f16x8 a[4], b[2];
            const unsigned int klane = (unsigned)(lane >> 4) * 16u + (unsigned)ks2 * 64u;
#pragma unroll
            for (int fm = 0; fm < 4; fm++) {
                const unsigned int row = (unsigned)(wr * 64 + fm * 16 + (lane & 15));
                const unsigned int off = (row * 128u + klane) ^ ((row & 7u) << 4);
                a[fm] = *(const f16x8*)((const char*)cA + off);
            }
#pragma unroll
            for (int fn = 0; fn < 2; fn++) {
                const unsigned int row = (unsigned)(wc * 32 + fn * 16 + (lane & 15));
                const unsigned int off = (row * 128u + klane) ^ ((row & 7u) << 4);
                b[fn] = *(const f16x8*)((const char*)cB + off);
            }
#pragma unroll
            for (int fm = 0; fm < 4; fm++)
#pragma unroll
                for (int fn = 0; fn < 2; fn++)
                    acc[fm][fn] = __builtin_amdgcn_mfma_f32_16x16x32_f16(a[fm], b[fn], acc[fm][fn], 0, 0, 0);
        }
        __syncthreads();   // drains lgkm (our ds_reads) + vmcnt (prefetch done)
        cur ^= 1;
    }

    // fp16 partial, 200-row pitch, rows >= kB skipped
    f16_t* po = part + (size_t)kc * ((size_t)kB * kNG);
#pragma unroll
    for (int fm = 0; fm < 4; fm++)
#pragma unroll
        for (int fn = 0; fn < 2; fn++) {
            const int row0 = m0 + wr * 64 + fm * 16 + ((lane >> 4) << 2);
            const int col  = n0 + wc * 32 + fn * 16 + (lane & 15);
#pragma unroll
            for (int j = 0; j < 4; j++) {
                const int row = row0 + j;
                if (row < kB)
                    po[(size_t)row * kNG + col] = (f16_t)acc[fm][fn][j];
            }
        }
}

// ---------------------------------------------------------------------------
// Reduce KSPLIT fp16 K-partials; mode 1: add velocity*W_ih^T, ReLU, store g
// (fp32 output) + fp16 g into gb[t] (which doubles as next step's A).
// mode 0 (encoder): write h0 to hout.  Grid: (4, kB), 256 thr, 4 g's/thread.
// ---------------------------------------------------------------------------
__global__ __launch_bounds__(256)
void k_reduce(const f16_t* __restrict__ part,
              const float* __restrict__ velocity, const float* __restrict__ W_ih,
              float* __restrict__ gout, f16_t* __restrict__ gb,
              f16_t* __restrict__ hout, int t, int mode) {
    const int b = blockIdx.y;
    const int g = blockIdx.x * 1024 + threadIdx.x * 4;

    float v0 = 0.f, v1 = 0.f, v2 = 0.f, v3 = 0.f;
#pragma unroll
    for (int ks = 0; ks < KSPLIT; ks++) {
        f16x4 p = *(const f16x4*)(part + (size_t)ks * ((size_t)kB * kNG) + (size_t)b * kNG + g);
        v0 += (float)p[0]; v1 += (float)p[1]; v2 += (float)p[2]; v3 += (float)p[3];
    }
    if (mode == 1) {
        const float2 vel = *(const float2*)(velocity + ((size_t)t * kB + b) * 2);
        const float4 w01 = *(const float4*)(W_ih + (size_t)g * 2);
        const float4 w23 = *(const float4*)(W_ih + (size_t)g * 2 + 4);
        v0 = fmaxf(0.f, v0 + vel.x * w01.x + vel.y * w01.y);
        v1 = fmaxf(0.f, v1 + vel.x * w01.z + vel.y * w01.w);
        v2 = fmaxf(0.f, v2 + vel.x * w23.x + vel.y * w23.y);
        v3 = fmaxf(0.f, v3 + vel.x * w23.z + vel.y * w23.w);
        float4 o; o.x = v0; o.y = v1; o.z = v2; o.w = v3;
        *(float4*)(gout + ((size_t)t * kB + b) * kNG + g) = o;
    }
    f16x4 h;
    h[0] = (f16_t)v0; h[1] = (f16_t)v1; h[2] = (f16_t)v2; h[3] = (f16_t)v3;
    if (hout)
        *(f16x4*)(hout + (size_t)b * kNG + g) = h;
    if (mode == 1 && gb)
        *(f16x4*)(gb + ((size_t)t * kB + b) * kNG + g) = h;
}

// ---------------------------------------------------------------------------
// Decoder (r5 proven form): logits[r][p] = sum_g G[r][g] * Wdec[p][g].
// LDS-staged with XOR swizzle; Gb (fp16 G) if non-null else Gf converted.
// Flat grid 632, XCD-colocated (4 n-tiles of an m-panel per XCD).
// ---------------------------------------------------------------------------
__global__ __launch_bounds__(256)
void k_dec(const float* __restrict__ Gf, const f16_t* __restrict__ Gb,
           const f16_t* __restrict__ Wd, float* __restrict__ out) {
    __shared__ __align__(16) f16_t sA[128 * 64];
    __shared__ __align__(16) f16_t sB[128 * 64];

    const int bid  = blockIdx.x;        // 0..631
    const int xcd  = bid & 7;
    const int idx  = bid >> 3;          // 0..78
    const int tile = xcd * 79 + idx;    // tile = m_t*4 + n_t
    if (tile >= 157 * 4) return;
    const int m0 = (tile >> 2) * 128;
    const int n0 = (tile & 3) * 128;

    const int tid  = threadIdx.x;
    const int lane = tid & 63;
    const int wid  = tid >> 6;
    const int wr   = wid >> 1;
    const int wc   = wid & 1;
    const int M    = kSEQ * kB;   // 20000

    f32x4 acc[4][4];
#pragma unroll
    for (int i = 0; i < 4; i++)
#pragma unroll
        for (int j = 0; j < 4; j++) acc[i][j] = (f32x4){0.f, 0.f, 0.f, 0.f};

    const int sr   = tid >> 1;
    const int half = tid & 1;
    const int sc   = half * 32;
    const unsigned int swzrow = ((unsigned)sr & 7u) << 4;
    const unsigned int sbase  = (unsigned)sr * 128u + (unsigned)half * 64u;
    int arow = m0 + sr; if (arow > M - 1) arow = M - 1;

    for (int k0 = 0; k0 < kNG; k0 += 64) {
        __syncthreads();
        if (Gb) {
            const uint4* gA = (const uint4*)(Gb + (size_t)arow * kNG + k0 + sc);
#pragma unroll
            for (int i = 0; i < 4; i++) {
                unsigned int off = (sbase + (unsigned)i * 16u) ^ swzrow;
                *(uint4*)((char*)sA + off) = gA[i];
            }
        } else {
            const float4* gA = (const float4*)(Gf + (size_t)arow * kNG + k0 + sc);
#pragma unroll
            for (int i = 0; i < 4; i++) {
                float4 a0 = gA[2 * i], a1 = gA[2 * i + 1];
                f16x8 u;
                u[0] = (f16_t)a0.x; u[1] = (f16_t)a0.y; u[2] = (f16_t)a0.z; u[3] = (f16_t)a0.w;
                u[4] = (f16_t)a1.x; u[5] = (f16_t)a1.y; u[6] = (f16_t)a1.z; u[7] = (f16_t)a1.w;
                unsigned int off = (sbase + (unsigned)i * 16u) ^ swzrow;
                *(f16x8*)((char*)sA + off) = u;
            }
        }
        {
            const uint4* gB = (const uint4*)(Wd + (size_t)(n0 + sr) * kNG + k0 + sc);
#pragma unroll
            for (int i = 0; i < 4; i++) {
                unsigned int off = (sbase + (unsigned)i * 16u) ^ swzrow;
                *(uint4*)((char*)sB + off) = gB[i];
            }
        }
        __syncthreads();
#pragma unroll
        for (int ks2 = 0; ks2 < 2; ks2++) {
            f16x8 a[4], b[4];
            const unsigned int klane = (unsigned)(lane >> 4) * 16u + (unsigned)ks2 * 64u;
#pragma unroll
            for (int fm = 0; fm < 4; fm++) {
                const unsigned int row = (unsigned)(wr * 64 + fm * 16 + (lane & 15));
                const unsigned int off = (row * 128u + klane) ^ ((row & 7u) << 4);
                a[fm] = *(const f16x8*)((const char*)sA + off);
            }
#pragma unroll
            for (int fn = 0; fn < 4; fn++) {
                const unsigned int row = (unsigned)(wc * 64 + fn * 16 + (lane & 15));
                const unsigned int off = (row * 128u + klane) ^ ((row & 7u) << 4);
                b[fn] = *(const f16x8*)((const char*)sB + off);
            }
#pragma unroll
            for (int fm = 0; fm < 4; fm++)
#pragma unroll
                for (int fn = 0; fn < 4; fn++)
                    acc[fm][fn] = __builtin_amdgcn_mfma_f32_16x16x32_f16(a[fm], b[fn], acc[fm][fn], 0, 0, 0);
        }
    }

#pragma unroll
    for (int fm = 0; fm < 4; fm++)
#pragma unroll
        for (int fn = 0; fn < 4; fn++) {
            const int row0 = m0 + wr * 64 + fm * 16 + ((lane >> 4) << 2);
            const int col  = n0 + wc * 64 + fn * 16 + (lane & 15);
#pragma unroll
            for (int j = 0; j < 4; j++) {
                const int row = row0 + j;
                if (row < M) out[(size_t)row * kNP + col] = acc[fm][fn][j];
            }
        }
}

// ---------------------------------------------------------------------------
extern "C" void kernel_launch(void* const* d_in, const int* in_sizes, int n_in,
                              void* d_out, int out_size, void* d_ws, size_t ws_size,
                              hipStream_t stream) {
    const float* velocity = (const float*)d_in[0];
    const float* init_pc  = (const float*)d_in[1];
    const float* W_enc    = (const float*)d_in[2];
    const float* W_ih     = (const float*)d_in[3];
    const float* W_hh     = (const float*)d_in[4];
    const float* W_dec    = (const float*)d_in[5];

    float* logits = (float*)d_out;                         // (100,200,512)
    float* gout   = logits + (size_t)kSEQ * kB * kNP;      // (100,200,4096)

    char* ws = (char*)d_ws;
    size_t off = 0;
    auto alloc = [&](size_t bytes) -> void* {
        void* p = ws + off;
        off += (bytes + 255) & ~(size_t)255;
        return p;
    };
    f16_t* whh  = (f16_t*)alloc((size_t)kNG * kNG * 2);
    f16_t* wdec = (f16_t*)alloc((size_t)kNP * kNG * 2);
    f16_t* wenc = (f16_t*)alloc((size_t)kNG * kNP * 2);
    f16_t* ip   = (f16_t*)alloc((size_t)kMP * kNP * 2);
    f16_t* h_buf[2];
    h_buf[0] = (f16_t*)alloc((size_t)kMP * kNG * 2);
    h_buf[1] = (f16_t*)alloc((size_t)kMP * kNG * 2);
    f16_t* partial = (f16_t*)alloc((size_t)KSPLIT * kB * kNG * 2);  // 13.1 MB fp16
    // fp16 g (doubles as the scan's h chain); +kMP rows pad for t=99 A-reads
    f16_t* gb = nullptr;
    if (ws_size >= off + ((size_t)kSEQ * kB + kMP) * kNG * 2 + 4096)
        gb = (f16_t*)alloc(((size_t)kSEQ * kB + kMP) * kNG * 2);

    // zero init_pc pad rows
    hipMemsetAsync(ip + (size_t)kB * kNP, 0, (size_t)(kMP - kB) * kNP * 2, stream);

    // --- fp32 -> fp16 conversions ---
    int n8;
    n8 = kNG * kNG / 8;
    k_half<<<(n8 + 255) / 256, 256, 0, stream>>>(W_hh, whh, n8);
    n8 = kNP * kNG / 8;
    k_half<<<(n8 + 255) / 256, 256, 0, stream>>>(W_dec, wdec, n8);
    n8 = kNG * kNP / 8;
    k_half<<<(n8 + 255) / 256, 256, 0, stream>>>(W_enc, wenc, n8);
    n8 = kB * kNP / 8;
    k_half<<<(n8 + 255) / 256, 256, 0, stream>>>(init_pc, ip, n8);

    dim3 gR(4, kB);

    // --- encoder: h0 = init_pc @ W_enc^T ---
    k_gemm_f16<<<512, 512, 0, stream>>>(ip, kNP, wenc, kNP, partial, kNP / KSPLIT);
    k_reduce<<<gR, 256, 0, stream>>>(partial, velocity, W_ih, nullptr, nullptr, h_buf[0], 0, 0);

    // --- recurrent scan (h chain lives inside gb when available) ---
    if (gb) {
        const f16_t* Acur = h_buf[0];
        for (int t = 0; t < kSEQ; t++) {
            k_gemm_f16<<<512, 512, 0, stream>>>(Acur, kNG, whh, kNG, partial, kNG / KSPLIT);
            k_reduce<<<gR, 256, 0, stream>>>(partial, velocity, W_ih, gout, gb, nullptr, t, 1);
            Acur = gb + (size_t)t * kB * kNG;
        }
    } else {
        int p = 0;
        for (int t = 0; t < kSEQ; t++) {
            k_gemm_f16<<<512, 512, 0, stream>>>(h_buf[p], kNG, whh, kNG, partial, kNG / KSPLIT);
            k_reduce<<<gR, 256, 0, stream>>>(partial, velocity, W_ih, gout, nullptr, h_buf[p ^ 1], t, 1);
            p ^= 1;
        }
    }

    // --- decoder ---
    k_dec<<<632, 256, 0, stream>>>(gout, gb, wdec, logits);
}